// Round 6
// baseline (265.812 us; speedup 1.0000x reference)
//
#include <hip/hip_runtime.h>
#include <hip/hip_bf16.h>
#include <cstddef>

#define NH 16
#define NKV 4
#define HD 128
#define SEQ 1024
#define SCALE_F 0.08838834764831845f
#define LOG2E 1.44269504088896f

typedef __attribute__((ext_vector_type(8))) short short8;
typedef __attribute__((ext_vector_type(4))) float floatx4;
typedef __attribute__((ext_vector_type(2))) unsigned int uintx2;

union F8 { short8 v; unsigned short u[8]; };

__device__ __forceinline__ unsigned short f2bf(float f) {
  unsigned int u = __float_as_uint(f);
  u += 0x7FFFu + ((u >> 16) & 1u);
  return (unsigned short)(u >> 16);
}

__device__ __forceinline__ unsigned int pkbf(float a, float b) {
  union { __hip_bfloat162 h; unsigned int u; } c;
  c.h = __float22bfloat162_rn(float2{a, b});  // a -> low 16, b -> high 16
  return c.u;
}

__device__ __forceinline__ void glds16(const void* g, void* l) {
  __builtin_amdgcn_global_load_lds(
      (const __attribute__((address_space(1))) unsigned int*)g,
      (__attribute__((address_space(3))) unsigned int*)l, 16, 0, 0);
}

// ---------------------------------------------------------------------------
// Pre-pass.
// K -> bf16 tiled+swizzled [512 tiles(32kpos)][32 kpos][16 d8-blk],
//   blk = kpos*16 + (d8 ^ (kpos&15)).  Each 4KB half (16 kpos) is a linear
//   DMA image; frag read slot = col*16 + ((ks*4+quad)^col).  [R3/R5-proven]
// V -> bf16 x32-A-frag order: per 32-kpos tile, slot s = dt*64 + lane
//   (lane = quad*16+col); content u[j] = V[kpos=quad*8+j][d=dt*16+col].
//   One global dwordx4 per (dt) IS the PV A-fragment — V skips LDS entirely.
// ---------------------------------------------------------------------------
__global__ __launch_bounds__(256) void prepass(const float* __restrict__ kg,
                                               const float* __restrict__ vg,
                                               unsigned short* __restrict__ Ktg,
                                               unsigned short* __restrict__ Vtg) {
  __shared__ float Vl[32 * 132];
  const int tid = threadIdx.x;
  const int bid = blockIdx.x;
  if (bid < 512) {
    const int bkvh = bid >> 5, tile = bid & 31;
    const int b = bkvh >> 2, kvh = bkvh & 3;
    const int kpos = tid >> 3;
    const int d8base = (tid & 7) * 2;
    const size_t tok = (size_t)b * SEQ + tile * 32 + kpos;
    const float* src = kg + (tok * NKV + kvh) * HD + d8base * 8;
    unsigned short* dstT = Ktg + (size_t)bid * 4096;
#pragma unroll
    for (int i = 0; i < 2; ++i) {
      floatx4 a = ((const floatx4*)src)[0];
      floatx4 c = ((const floatx4*)src)[1];
      F8 t;
#pragma unroll
      for (int j = 0; j < 4; ++j) { t.u[j] = f2bf(a[j]); t.u[4 + j] = f2bf(c[j]); }
      const int blk = kpos * 16 + ((d8base + i) ^ (kpos & 15));
      *(short8*)(dstT + blk * 8) = t.v;
      src += 8;
    }
  } else {
    const int bb2 = bid - 512;
    const int bkvh = bb2 >> 5, tile = bb2 & 31;
    const int b = bkvh >> 2, kvh = bkvh & 3;
    const int r = tid >> 3;
    const int c16 = (tid & 7) * 16;
    const size_t tok = (size_t)b * SEQ + tile * 32 + r;
    const float* src = vg + (tok * NKV + kvh) * HD + c16;
#pragma unroll
    for (int j = 0; j < 4; ++j)
      *(floatx4*)&Vl[r * 132 + c16 + j * 4] = ((const floatx4*)src)[j];
    __syncthreads();
    unsigned short* dstT = Vtg + (size_t)bb2 * 4096;
#pragma unroll
    for (int i = 0; i < 2; ++i) {
      const int s = tid * 2 + i;        // slot 0..511
      const int dt = s >> 6;
      const int ln = s & 63;
      const int qd = ln >> 4;           // reading lane's quad
      const int cl = ln & 15;           // reading lane's col (d_local)
      F8 t;
#pragma unroll
      for (int j = 0; j < 8; ++j)
        t.u[j] = f2bf(Vl[(qd * 8 + j) * 132 + dt * 16 + cl]);
      *(short8*)(dstT + s * 8) = t.v;
    }
  }
}

// ---------------------------------------------------------------------------
// Hot kernel: grid 2048 x 128 thr (2 waves).  Block = one 32-row q-tile; the
// two waves share the q-rows and split 32-kpos k-pairs by parity (max-free
// softmax => k-decomposition is a pure sum; combined once at the end).
// 8 blocks/CU -> 16 waves/CU.  No __syncthreads in the K-loop: K staged via
// wave-private dbuf-less 8KB buffer + explicit vmcnt(0); V read as global
// dwordx4 fragments; P^T round-trips a wave-private 2KB LDS buffer (xor-
// swizzled, b64 writes / b128 reads) to feed x32 PV MFMAs.
// ---------------------------------------------------------------------------
__global__ __launch_bounds__(128, 4)
void fa_fwd4(const float* __restrict__ qg, const unsigned short* __restrict__ Ktg,
             const unsigned short* __restrict__ Vtg, float* __restrict__ og) {
  __shared__ __align__(16) unsigned short Kb[2][4096];  // [wave][8KB K pair]
  __shared__ __align__(16) unsigned int Pbuf[2][512];   // [wave][32 q x 16 dw]

  const int tid = threadIdx.x;
  const int w = tid >> 6;
  const int lane = tid & 63;
  const int col = lane & 15;
  const int quad = lane >> 4;

  const int idx = blockIdx.x;
  // Balance: qt = j*4 + ((u2+j)&3); per-CU (round-robin) and per-XCD (%8)
  // co-resident qt sums are constant (124) -> uniform 132 pair-tiles/CU.
  const int jj = idx >> 8;
  const int u = idx & 255;
  const int bh = u >> 2;
  const int qt = jj * 4 + (((u & 3) + jj) & 3);  // 0..31
  const int h = bh & 15;
  const int b = bh >> 4;
  const int kvh = h >> 2;
  const int seg = b * SEQ;
  const int q0 = qt * 32;
  const size_t tbase = (size_t)((b * NKV + kvh) * 32) * 8192;

  // Q B-frags [n=q=col][k=quad*8+j], scaled by SCALE*log2e
  F8 qf[2][4];
#pragma unroll
  for (int nt = 0; nt < 2; ++nt) {
    const float* qp =
        qg + ((size_t)(seg + q0 + nt * 16 + col) * NH + h) * HD + quad * 8;
#pragma unroll
    for (int ks = 0; ks < 4; ++ks) {
      floatx4 a = ((const floatx4*)(qp + ks * 32))[0];
      floatx4 c = ((const floatx4*)(qp + ks * 32))[1];
#pragma unroll
      for (int j = 0; j < 4; ++j) {
        qf[nt][ks].u[j] = f2bf(a[j] * (SCALE_F * LOG2E));
        qf[nt][ks].u[4 + j] = f2bf(c[j] * (SCALE_F * LOG2E));
      }
    }
  }

  floatx4 acc[2][8];
#pragma unroll
  for (int nt = 0; nt < 2; ++nt)
#pragma unroll
    for (int dt = 0; dt < 8; ++dt) acc[nt][dt] = (floatx4){0.f, 0.f, 0.f, 0.f};
  float lsum[2] = {0.f, 0.f};

  char* lk = (char*)&Kb[w][0];
  if (w <= qt) {  // prologue DMA: this wave's first pair
    const char* gk = (const char*)Ktg + tbase + (size_t)w * 8192 + lane * 16;
#pragma unroll
    for (int o = 0; o < 8192; o += 1024) glds16(gk + o, lk + o);
  }

  for (int p = w; p <= qt; p += 2) {
    __builtin_amdgcn_s_waitcnt(0x0f70);  // vmcnt(0): K DMA for pair p done
    __builtin_amdgcn_sched_barrier(0);
    // V fragments: global dwordx4 straight from frag-ordered Vtg (L2-hot)
    F8 vf[8];
    const char* vsrc = (const char*)Vtg + tbase + (size_t)p * 8192 + lane * 16;
#pragma unroll
    for (int dt = 0; dt < 8; ++dt) vf[dt].v = *(const short8*)(vsrc + dt * 1024);
    // ---- QK^T -> S^T over two 16-kpos halves ----
    floatx4 st[2][2];  // [nt][half]
#pragma unroll
    for (int nt = 0; nt < 2; ++nt)
#pragma unroll
      for (int hh = 0; hh < 2; ++hh) st[nt][hh] = (floatx4){0.f, 0.f, 0.f, 0.f};
#pragma unroll
    for (int hh = 0; hh < 2; ++hh)
#pragma unroll
      for (int ks = 0; ks < 4; ++ks) {
        F8 kf;
        kf.v = *(const short8*)&Kb[w][hh * 2048 +
                                      (col * 16 + ((ks * 4 + quad) ^ col)) * 8];
        st[0][hh] = __builtin_amdgcn_mfma_f32_16x16x32_bf16(
            kf.v, qf[0][ks].v, st[0][hh], 0, 0, 0);
        st[1][hh] = __builtin_amdgcn_mfma_f32_16x16x32_bf16(
            kf.v, qf[1][ks].v, st[1][hh], 0, 0, 0);
      }
    // ---- softmax (max-free, exp2) + P^T pack to wave-private LDS ----
    const bool diag = (p == qt);
#pragma unroll
    for (int nt = 0; nt < 2; ++nt)
#pragma unroll
      for (int hh = 0; hh < 2; ++hh) {
        float pr[4];
#pragma unroll
        for (int r = 0; r < 4; ++r) {
          pr[r] = exp2f(st[nt][hh][r]);
          if (diag && (p * 32 + hh * 16 + quad * 4 + r > q0 + nt * 16 + col))
            pr[r] = 0.f;
        }
        lsum[nt] += (pr[0] + pr[1]) + (pr[2] + pr[3]);
        // logical dword (kpos/2) = hh*8+quad*2; 4-dw block bb xor-swizzled
        const int bbi = hh * 2 + (quad >> 1);
        unsigned int* pw = &Pbuf[w][(nt * 16 + col) * 16 +
                                    ((bbi ^ (col & 3)) << 2) + ((quad & 1) << 1)];
        *(uintx2*)pw = (uintx2){pkbf(pr[0], pr[1]), pkbf(pr[2], pr[3])};
      }
    // ---- P^T B-frags: one b128 per nt (k = quad*8+j over full 32 kpos) ----
    F8 pb[2];
#pragma unroll
    for (int nt = 0; nt < 2; ++nt)
      pb[nt].v = *(const short8*)&Pbuf[w][(nt * 16 + col) * 16 +
                                          ((quad ^ (col & 3)) << 2)];
    __builtin_amdgcn_sched_barrier(0);
    // prefetch next K pair (overlaps PV + next-pair V/QK issue)
    if (p + 2 <= qt) {
      const char* gk =
          (const char*)Ktg + tbase + (size_t)(p + 2) * 8192 + lane * 16;
#pragma unroll
      for (int o = 0; o < 8192; o += 1024) glds16(gk + o, lk + o);
    }
    // ---- PV: x32, A = V^T frag, B = P^T frag ----
#pragma unroll
    for (int dt = 0; dt < 8; ++dt)
#pragma unroll
      for (int nt = 0; nt < 2; ++nt)
        acc[nt][dt] = __builtin_amdgcn_mfma_f32_16x16x32_bf16(
            vf[dt].v, pb[nt].v, acc[nt][dt], 0, 0, 0);
  }

  // ---- combine the two k-parity waves, normalize, store ----
  __syncthreads();
  float* cb = (float*)&Kb[0][0];        // 16KB: exactly one wave's acc
  float* lb = (float*)&Pbuf[0][0];
  if (w == 1) {
#pragma unroll
    for (int nt = 0; nt < 2; ++nt)
#pragma unroll
      for (int dt = 0; dt < 8; ++dt)
        *(floatx4*)&cb[((nt * 8 + dt) * 64 + lane) * 4] = acc[nt][dt];
    lb[lane] = lsum[0];
    lb[64 + lane] = lsum[1];
  }
  __syncthreads();
  if (w == 0) {
#pragma unroll
    for (int nt = 0; nt < 2; ++nt) {
      float l = lsum[nt] + lb[nt * 64 + lane];
      l += __shfl_xor(l, 16);
      l += __shfl_xor(l, 32);
      const float inv = 1.0f / l;
      float* op = og + ((size_t)(seg + q0 + nt * 16 + col) * NH + h) * HD +
                  quad * 4;
#pragma unroll
      for (int dt = 0; dt < 8; ++dt) {
        floatx4 o = acc[nt][dt] + *(const floatx4*)&cb[((nt * 8 + dt) * 64 + lane) * 4];
        o[0] *= inv; o[1] *= inv; o[2] *= inv; o[3] *= inv;
        *(floatx4*)(op + dt * 16) = o;
      }
    }
  }
}

// ---------------------------------------------------------------------------
// Fallback (R2 kernel) if d_ws is too small for the pre-pass buffers.
// ---------------------------------------------------------------------------
#define KST 136
#define VST 40
#define PST 40

__global__ __launch_bounds__(256, 2)
void fa_fwd(const float* __restrict__ qg, const float* __restrict__ kg,
            const float* __restrict__ vg, float* __restrict__ og) {
  __shared__ unsigned short Klds[32 * KST];
  __shared__ unsigned short Vt[HD * VST];
  __shared__ unsigned short Pl[4][32 * PST];

  const int tid = threadIdx.x;
  const int wave = tid >> 6;
  const int lane = tid & 63;
  const int col = lane & 15;
  const int quad = lane >> 4;

  const int idx = blockIdx.x;
  const int raw = idx & 7;
  const int qt = (idx & 256) ? raw : 7 - raw;
  const int bh = idx >> 3;
  const int h = bh & 15;
  const int b = bh >> 4;
  const int kvh = h >> 2;
  const int seg = b * SEQ;
  const int wq0 = qt * 128 + wave * 32;

  F8 qf[2][4];
#pragma unroll
  for (int mt = 0; mt < 2; ++mt) {
    const size_t qrow = (size_t)(seg + wq0 + mt * 16 + col);
    const float* qp = qg + (qrow * NH + h) * HD + quad * 8;
#pragma unroll
    for (int ks = 0; ks < 4; ++ks) {
      const floatx4* p4 = (const floatx4*)(qp + ks * 32);
      floatx4 a = p4[0], c = p4[1];
#pragma unroll
      for (int j = 0; j < 4; ++j) {
        qf[mt][ks].u[j] = f2bf(a[j] * SCALE_F);
        qf[mt][ks].u[4 + j] = f2bf(c[j] * SCALE_F);
      }
    }
  }

  floatx4 acc[2][8];
#pragma unroll
  for (int mt = 0; mt < 2; ++mt)
#pragma unroll
    for (int dt = 0; dt < 8; ++dt)
      acc[mt][dt] = (floatx4){0.f, 0.f, 0.f, 0.f};
  float lsum[2][4];
#pragma unroll
  for (int mt = 0; mt < 2; ++mt)
#pragma unroll
    for (int r = 0; r < 4; ++r) lsum[mt][r] = 0.f;

  const int nkt = 4 * (qt + 1);
  const int sr = tid >> 3;
  const int sc = (tid & 7) * 16;

  for (int kt = 0; kt < nkt; ++kt) {
    const int kbase = kt * 32;
    __syncthreads();
    {
      const size_t tok = (size_t)(seg + kbase + sr);
      const floatx4* kp4 = (const floatx4*)(kg + (tok * NKV + kvh) * HD + sc);
      floatx4 kv0 = kp4[0], kv1 = kp4[1], kv2 = kp4[2], kv3 = kp4[3];
      float kf32[16] = {kv0[0],kv0[1],kv0[2],kv0[3], kv1[0],kv1[1],kv1[2],kv1[3],
                        kv2[0],kv2[1],kv2[2],kv2[3], kv3[0],kv3[1],kv3[2],kv3[3]};
      unsigned int* dst = (unsigned int*)&Klds[sr * KST + sc];
#pragma unroll
      for (int j = 0; j < 8; ++j)
        dst[j] = (unsigned int)f2bf(kf32[2 * j]) | ((unsigned int)f2bf(kf32[2 * j + 1]) << 16);
      const floatx4* vp4 = (const floatx4*)(vg + (tok * NKV + kvh) * HD + sc);
      floatx4 vv0 = vp4[0], vv1 = vp4[1], vv2 = vp4[2], vv3 = vp4[3];
      unsigned short vb[16] = {
        f2bf(vv0[0]),f2bf(vv0[1]),f2bf(vv0[2]),f2bf(vv0[3]),
        f2bf(vv1[0]),f2bf(vv1[1]),f2bf(vv1[2]),f2bf(vv1[3]),
        f2bf(vv2[0]),f2bf(vv2[1]),f2bf(vv2[2]),f2bf(vv2[3]),
        f2bf(vv3[0]),f2bf(vv3[1]),f2bf(vv3[2]),f2bf(vv3[3])};
#pragma unroll
      for (int s = 0; s < 16; ++s) {
        int j = (s + tid) & 15;
        Vt[(sc + j) * VST + sr] = vb[j];
      }
    }
    __syncthreads();

    if (kbase > wq0 + 31) continue;

    F8 kf[4][2];
#pragma unroll
    for (int ks = 0; ks < 4; ++ks)
#pragma unroll
      for (int nt = 0; nt < 2; ++nt)
        kf[ks][nt].v = *(const short8*)&Klds[(nt * 16 + col) * KST + ks * 32 + quad * 8];

#pragma unroll
    for (int mt = 0; mt < 2; ++mt) {
      floatx4 s0 = {0.f, 0.f, 0.f, 0.f}, s1 = {0.f, 0.f, 0.f, 0.f};
#pragma unroll
      for (int ks = 0; ks < 4; ++ks) {
        s0 = __builtin_amdgcn_mfma_f32_16x16x32_bf16(qf[mt][ks].v, kf[ks][0].v, s0, 0, 0, 0);
        s1 = __builtin_amdgcn_mfma_f32_16x16x32_bf16(qf[mt][ks].v, kf[ks][1].v, s1, 0, 0, 0);
      }
      const int q0 = wq0 + mt * 16 + quad * 4;
      const bool diag = (kbase + 31 > wq0 + mt * 16);
      unsigned short* pw = &Pl[wave][(mt * 16 + quad * 4) * PST];
#pragma unroll
      for (int r = 0; r < 4; ++r) {
        float p0 = __expf(s0[r]);
        float p1 = __expf(s1[r]);
        if (diag) {
          p0 = (kbase + col > q0 + r) ? 0.f : p0;
          p1 = (kbase + 16 + col > q0 + r) ? 0.f : p1;
        }
        lsum[mt][r] += p0 + p1;
        pw[r * PST + col] = f2bf(p0);
        pw[r * PST + 16 + col] = f2bf(p1);
      }
    }
    F8 pa[2];
#pragma unroll
    for (int mt = 0; mt < 2; ++mt)
      pa[mt].v = *(const short8*)&Pl[wave][(mt * 16 + col) * PST + quad * 8];
#pragma unroll
    for (int dt = 0; dt < 8; ++dt) {
      F8 vb;
      vb.v = *(const short8*)&Vt[(dt * 16 + col) * VST + quad * 8];
#pragma unroll
      for (int mt = 0; mt < 2; ++mt)
        acc[mt][dt] = __builtin_amdgcn_mfma_f32_16x16x32_bf16(pa[mt].v, vb.v, acc[mt][dt], 0, 0, 0);
    }
  }

#pragma unroll
  for (int mt = 0; mt < 2; ++mt) {
#pragma unroll
    for (int r = 0; r < 4; ++r) {
      float l = lsum[mt][r];
      l += __shfl_xor(l, 1);
      l += __shfl_xor(l, 2);
      l += __shfl_xor(l, 4);
      l += __shfl_xor(l, 8);
      const float inv = 1.0f / l;
      const int qi = wq0 + mt * 16 + quad * 4 + r;
      float* op = og + ((size_t)(seg + qi) * NH + h) * HD;
#pragma unroll
      for (int dt = 0; dt < 8; ++dt)
        op[dt * 16 + col] = acc[mt][dt][r] * inv;
    }
  }
}

extern "C" void kernel_launch(void* const* d_in, const int* in_sizes, int n_in,
                              void* d_out, int out_size, void* d_ws, size_t ws_size,
                              hipStream_t stream) {
  const float* q = (const float*)d_in[0];
  const float* k = (const float*)d_in[1];
  const float* v = (const float*)d_in[2];
  float* out = (float*)d_out;
  if (ws_size >= (size_t)(8 * 1024 * 1024)) {
    unsigned short* Ktg = (unsigned short*)d_ws;
    unsigned short* Vtg = Ktg + 2097152;  // +4MB
    hipLaunchKernelGGL(prepass, dim3(1024), dim3(256), 0, stream, k, v, Ktg, Vtg);
    hipLaunchKernelGGL(fa_fwd4, dim3(2048), dim3(128), 0, stream, q, Ktg, Vtg, out);
  } else {
    hipLaunchKernelGGL(fa_fwd, dim3(512), dim3(256), 0, stream, q, k, v, out);
  }
}

// Round 7
// 143.039 us; speedup vs baseline: 1.8583x; 1.8583x over previous
//
#include <hip/hip_runtime.h>
#include <hip/hip_bf16.h>
#include <cstddef>

#define NH 16
#define NKV 4
#define HD 128
#define SEQ 1024
#define SCALE_F 0.08838834764831845f
#define LOG2E 1.44269504088896f

typedef __attribute__((ext_vector_type(8))) short short8;
typedef __attribute__((ext_vector_type(4))) float floatx4;
typedef __attribute__((ext_vector_type(2))) unsigned int uintx2;

union F8 { short8 v; unsigned short u[8]; };

__device__ __forceinline__ unsigned short f2bf(float f) {
  unsigned int u = __float_as_uint(f);
  u += 0x7FFFu + ((u >> 16) & 1u);
  return (unsigned short)(u >> 16);
}

__device__ __forceinline__ unsigned int pkbf(float a, float b) {
  union { __hip_bfloat162 h; unsigned int u; } c;
  c.h = __float22bfloat162_rn(float2{a, b});  // a -> low 16, b -> high 16
  return c.u;
}

__device__ __forceinline__ void glds16(const void* g, void* l) {
  __builtin_amdgcn_global_load_lds(
      (const __attribute__((address_space(1))) unsigned int*)g,
      (__attribute__((address_space(3))) unsigned int*)l, 16, 0, 0);
}

// ---------------------------------------------------------------------------
// Pre-pass (unchanged from R6 — layouts correctness-proven).
// K -> bf16 tiled+swizzled [512 tiles(32kpos)][32 kpos][16 d8-blk],
//   blk = kpos*16 + (d8 ^ (kpos&15)).
// V -> bf16 x32-A-frag order: slot s = dt*64 + lane; u[j] =
//   V[kpos=quad*8+j][d=dt*16+col].  One global dwordx4 IS the PV A-frag.
// ---------------------------------------------------------------------------
__global__ __launch_bounds__(256) void prepass(const float* __restrict__ kg,
                                               const float* __restrict__ vg,
                                               unsigned short* __restrict__ Ktg,
                                               unsigned short* __restrict__ Vtg) {
  __shared__ float Vl[32 * 132];
  const int tid = threadIdx.x;
  const int bid = blockIdx.x;
  if (bid < 512) {
    const int bkvh = bid >> 5, tile = bid & 31;
    const int b = bkvh >> 2, kvh = bkvh & 3;
    const int kpos = tid >> 3;
    const int d8base = (tid & 7) * 2;
    const size_t tok = (size_t)b * SEQ + tile * 32 + kpos;
    const float* src = kg + (tok * NKV + kvh) * HD + d8base * 8;
    unsigned short* dstT = Ktg + (size_t)bid * 4096;
#pragma unroll
    for (int i = 0; i < 2; ++i) {
      floatx4 a = ((const floatx4*)src)[0];
      floatx4 c = ((const floatx4*)src)[1];
      F8 t;
#pragma unroll
      for (int j = 0; j < 4; ++j) { t.u[j] = f2bf(a[j]); t.u[4 + j] = f2bf(c[j]); }
      const int blk = kpos * 16 + ((d8base + i) ^ (kpos & 15));
      *(short8*)(dstT + blk * 8) = t.v;
      src += 8;
    }
  } else {
    const int bb2 = bid - 512;
    const int bkvh = bb2 >> 5, tile = bb2 & 31;
    const int b = bkvh >> 2, kvh = bkvh & 3;
    const int r = tid >> 3;
    const int c16 = (tid & 7) * 16;
    const size_t tok = (size_t)b * SEQ + tile * 32 + r;
    const float* src = vg + (tok * NKV + kvh) * HD + c16;
#pragma unroll
    for (int j = 0; j < 4; ++j)
      *(floatx4*)&Vl[r * 132 + c16 + j * 4] = ((const floatx4*)src)[j];
    __syncthreads();
    unsigned short* dstT = Vtg + (size_t)bb2 * 4096;
#pragma unroll
    for (int i = 0; i < 2; ++i) {
      const int s = tid * 2 + i;        // slot 0..511
      const int dt = s >> 6;
      const int ln = s & 63;
      const int qd = ln >> 4;
      const int cl = ln & 15;
      F8 t;
#pragma unroll
      for (int j = 0; j < 8; ++j)
        t.u[j] = f2bf(Vl[(qd * 8 + j) * 132 + dt * 16 + cl]);
      *(short8*)(dstT + s * 8) = t.v;
    }
  }
}

// ---------------------------------------------------------------------------
// Hot kernel (R6 structure, spill-fixed): grid 2048 x 128 thr (2 waves).
// Block = one 32-row q-tile; waves split 32-kpos pairs by parity (max-free
// softmax => k-split is a pure sum, combined at the end).  No __syncthreads
// in the K-loop.  launch_bounds(128,3): 170-reg budget fits the ~160 live
// regs (64 AGPR acc + ~95 VGPR) -- (128,4)'s 128 budget caused 300MB of
// scratch spill traffic in R6.
// ---------------------------------------------------------------------------
__global__ __launch_bounds__(128, 3)
void fa_fwd4(const float* __restrict__ qg, const unsigned short* __restrict__ Ktg,
             const unsigned short* __restrict__ Vtg, float* __restrict__ og) {
  __shared__ __align__(16) unsigned short Kb[2][4096];  // [wave][8KB K pair]
  __shared__ __align__(16) unsigned int Pbuf[2][512];   // [wave][32 q x 16 dw]

  const int tid = threadIdx.x;
  const int w = tid >> 6;
  const int lane = tid & 63;
  const int col = lane & 15;
  const int quad = lane >> 4;

  const int idx = blockIdx.x;
  // Longest-first (LPT): qt=31 blocks dispatched first; backfill smooths
  // the tail with 6 resident blocks/CU.
  const int qt = 31 - (idx >> 6);
  const int bh = idx & 63;
  const int h = bh & 15;
  const int b = bh >> 4;
  const int kvh = h >> 2;
  const int seg = b * SEQ;
  const int q0 = qt * 32;
  const size_t tbase = (size_t)((b * NKV + kvh) * 32) * 8192;

  // Q B-frags [n=q=col][k=quad*8+j], scaled by SCALE*log2e
  F8 qf[2][4];
#pragma unroll
  for (int nt = 0; nt < 2; ++nt) {
    const float* qp =
        qg + ((size_t)(seg + q0 + nt * 16 + col) * NH + h) * HD + quad * 8;
#pragma unroll
    for (int ks = 0; ks < 4; ++ks) {
      floatx4 a = ((const floatx4*)(qp + ks * 32))[0];
      floatx4 c = ((const floatx4*)(qp + ks * 32))[1];
#pragma unroll
      for (int j = 0; j < 4; ++j) {
        qf[nt][ks].u[j] = f2bf(a[j] * (SCALE_F * LOG2E));
        qf[nt][ks].u[4 + j] = f2bf(c[j] * (SCALE_F * LOG2E));
      }
    }
  }

  floatx4 acc[2][8];
#pragma unroll
  for (int nt = 0; nt < 2; ++nt)
#pragma unroll
    for (int dt = 0; dt < 8; ++dt) acc[nt][dt] = (floatx4){0.f, 0.f, 0.f, 0.f};
  float lsum[2] = {0.f, 0.f};

  char* lk = (char*)&Kb[w][0];
  if (w <= qt) {  // prologue DMA: this wave's first pair
    const char* gk = (const char*)Ktg + tbase + (size_t)w * 8192 + lane * 16;
#pragma unroll
    for (int o = 0; o < 8192; o += 1024) glds16(gk + o, lk + o);
  }

  for (int p = w; p <= qt; p += 2) {
    __builtin_amdgcn_s_waitcnt(0x0f70);  // vmcnt(0): K DMA for pair p landed
    __builtin_amdgcn_sched_barrier(0);
    // V fragments: global dwordx4 straight from frag-ordered Vtg (L2-hot)
    F8 vf[8];
    const char* vsrc = (const char*)Vtg + tbase + (size_t)p * 8192 + lane * 16;
#pragma unroll
    for (int dt = 0; dt < 8; ++dt) vf[dt].v = *(const short8*)(vsrc + dt * 1024);
    // ---- QK^T -> S^T over two 16-kpos halves ----
    floatx4 st[2][2];  // [nt][half]
#pragma unroll
    for (int nt = 0; nt < 2; ++nt)
#pragma unroll
      for (int hh = 0; hh < 2; ++hh) st[nt][hh] = (floatx4){0.f, 0.f, 0.f, 0.f};
#pragma unroll
    for (int hh = 0; hh < 2; ++hh)
#pragma unroll
      for (int ks = 0; ks < 4; ++ks) {
        F8 kf;
        kf.v = *(const short8*)&Kb[w][hh * 2048 +
                                      (col * 16 + ((ks * 4 + quad) ^ col)) * 8];
        st[0][hh] = __builtin_amdgcn_mfma_f32_16x16x32_bf16(
            kf.v, qf[0][ks].v, st[0][hh], 0, 0, 0);
        st[1][hh] = __builtin_amdgcn_mfma_f32_16x16x32_bf16(
            kf.v, qf[1][ks].v, st[1][hh], 0, 0, 0);
      }
    __builtin_amdgcn_sched_barrier(0);
    // prefetch next K pair NOW: kf ds_reads fully consumed by the QK mfmas
    // above; DMA gets ~400 extra cycles in flight before next vmcnt(0).
    if (p + 2 <= qt) {
      const char* gk =
          (const char*)Ktg + tbase + (size_t)(p + 2) * 8192 + lane * 16;
#pragma unroll
      for (int o = 0; o < 8192; o += 1024) glds16(gk + o, lk + o);
    }
    __builtin_amdgcn_sched_barrier(0);
    // ---- softmax (max-free, exp2) + P^T pack to wave-private LDS ----
    const bool diag = (p == qt);
#pragma unroll
    for (int nt = 0; nt < 2; ++nt)
#pragma unroll
      for (int hh = 0; hh < 2; ++hh) {
        float pr[4];
#pragma unroll
        for (int r = 0; r < 4; ++r) {
          pr[r] = exp2f(st[nt][hh][r]);
          if (diag && (p * 32 + hh * 16 + quad * 4 + r > q0 + nt * 16 + col))
            pr[r] = 0.f;
        }
        lsum[nt] += (pr[0] + pr[1]) + (pr[2] + pr[3]);
        const int bbi = hh * 2 + (quad >> 1);
        unsigned int* pw = &Pbuf[w][(nt * 16 + col) * 16 +
                                    ((bbi ^ (col & 3)) << 2) + ((quad & 1) << 1)];
        *(uintx2*)pw = (uintx2){pkbf(pr[0], pr[1]), pkbf(pr[2], pr[3])};
      }
    // ---- P^T B-frags: one b128 per nt (k = quad*8+j over full 32 kpos) ----
    F8 pb[2];
#pragma unroll
    for (int nt = 0; nt < 2; ++nt)
      pb[nt].v = *(const short8*)&Pbuf[w][(nt * 16 + col) * 16 +
                                          ((quad ^ (col & 3)) << 2)];
    // ---- PV: x32, A = V^T frag, B = P^T frag ----
#pragma unroll
    for (int dt = 0; dt < 8; ++dt)
#pragma unroll
      for (int nt = 0; nt < 2; ++nt)
        acc[nt][dt] = __builtin_amdgcn_mfma_f32_16x16x32_bf16(
            vf[dt].v, pb[nt].v, acc[nt][dt], 0, 0, 0);
  }

  // ---- combine the two k-parity waves, normalize, store ----
  __syncthreads();
  float* cb = (float*)&Kb[0][0];        // 16KB: exactly one wave's acc
  float* lb = (float*)&Pbuf[0][0];
  if (w == 1) {
#pragma unroll
    for (int nt = 0; nt < 2; ++nt)
#pragma unroll
      for (int dt = 0; dt < 8; ++dt)
        *(floatx4*)&cb[((nt * 8 + dt) * 64 + lane) * 4] = acc[nt][dt];
    lb[lane] = lsum[0];
    lb[64 + lane] = lsum[1];
  }
  __syncthreads();
  if (w == 0) {
#pragma unroll
    for (int nt = 0; nt < 2; ++nt) {
      float l = lsum[nt] + lb[nt * 64 + lane];
      l += __shfl_xor(l, 16);
      l += __shfl_xor(l, 32);
      const float inv = 1.0f / l;
      float* op = og + ((size_t)(seg + q0 + nt * 16 + col) * NH + h) * HD +
                  quad * 4;
#pragma unroll
      for (int dt = 0; dt < 8; ++dt) {
        floatx4 o = acc[nt][dt] + *(const floatx4*)&cb[((nt * 8 + dt) * 64 + lane) * 4];
        o[0] *= inv; o[1] *= inv; o[2] *= inv; o[3] *= inv;
        *(floatx4*)(op + dt * 16) = o;
      }
    }
  }
}

// ---------------------------------------------------------------------------
// Fallback (R2 kernel) if d_ws is too small for the pre-pass buffers.
// ---------------------------------------------------------------------------
#define KST 136
#define VST 40
#define PST 40

__global__ __launch_bounds__(256, 2)
void fa_fwd(const float* __restrict__ qg, const float* __restrict__ kg,
            const float* __restrict__ vg, float* __restrict__ og) {
  __shared__ unsigned short Klds[32 * KST];
  __shared__ unsigned short Vt[HD * VST];
  __shared__ unsigned short Pl[4][32 * PST];

  const int tid = threadIdx.x;
  const int wave = tid >> 6;
  const int lane = tid & 63;
  const int col = lane & 15;
  const int quad = lane >> 4;

  const int idx = blockIdx.x;
  const int raw = idx & 7;
  const int qt = (idx & 256) ? raw : 7 - raw;
  const int bh = idx >> 3;
  const int h = bh & 15;
  const int b = bh >> 4;
  const int kvh = h >> 2;
  const int seg = b * SEQ;
  const int wq0 = qt * 128 + wave * 32;

  F8 qf[2][4];
#pragma unroll
  for (int mt = 0; mt < 2; ++mt) {
    const size_t qrow = (size_t)(seg + wq0 + mt * 16 + col);
    const float* qp = qg + (qrow * NH + h) * HD + quad * 8;
#pragma unroll
    for (int ks = 0; ks < 4; ++ks) {
      const floatx4* p4 = (const floatx4*)(qp + ks * 32);
      floatx4 a = p4[0], c = p4[1];
#pragma unroll
      for (int j = 0; j < 4; ++j) {
        qf[mt][ks].u[j] = f2bf(a[j] * SCALE_F);
        qf[mt][ks].u[4 + j] = f2bf(c[j] * SCALE_F);
      }
    }
  }

  floatx4 acc[2][8];
#pragma unroll
  for (int mt = 0; mt < 2; ++mt)
#pragma unroll
    for (int dt = 0; dt < 8; ++dt)
      acc[mt][dt] = (floatx4){0.f, 0.f, 0.f, 0.f};
  float lsum[2][4];
#pragma unroll
  for (int mt = 0; mt < 2; ++mt)
#pragma unroll
    for (int r = 0; r < 4; ++r) lsum[mt][r] = 0.f;

  const int nkt = 4 * (qt + 1);
  const int sr = tid >> 3;
  const int sc = (tid & 7) * 16;

  for (int kt = 0; kt < nkt; ++kt) {
    const int kbase = kt * 32;
    __syncthreads();
    {
      const size_t tok = (size_t)(seg + kbase + sr);
      const floatx4* kp4 = (const floatx4*)(kg + (tok * NKV + kvh) * HD + sc);
      floatx4 kv0 = kp4[0], kv1 = kp4[1], kv2 = kp4[2], kv3 = kp4[3];
      float kf32[16] = {kv0[0],kv0[1],kv0[2],kv0[3], kv1[0],kv1[1],kv1[2],kv1[3],
                        kv2[0],kv2[1],kv2[2],kv2[3], kv3[0],kv3[1],kv3[2],kv3[3]};
      unsigned int* dst = (unsigned int*)&Klds[sr * KST + sc];
#pragma unroll
      for (int j = 0; j < 8; ++j)
        dst[j] = (unsigned int)f2bf(kf32[2 * j]) | ((unsigned int)f2bf(kf32[2 * j + 1]) << 16);
      const floatx4* vp4 = (const floatx4*)(vg + (tok * NKV + kvh) * HD + sc);
      floatx4 vv0 = vp4[0], vv1 = vp4[1], vv2 = vp4[2], vv3 = vp4[3];
      unsigned short vb[16] = {
        f2bf(vv0[0]),f2bf(vv0[1]),f2bf(vv0[2]),f2bf(vv0[3]),
        f2bf(vv1[0]),f2bf(vv1[1]),f2bf(vv1[2]),f2bf(vv1[3]),
        f2bf(vv2[0]),f2bf(vv2[1]),f2bf(vv2[2]),f2bf(vv2[3]),
        f2bf(vv3[0]),f2bf(vv3[1]),f2bf(vv3[2]),f2bf(vv3[3])};
#pragma unroll
      for (int s = 0; s < 16; ++s) {
        int j = (s + tid) & 15;
        Vt[(sc + j) * VST + sr] = vb[j];
      }
    }
    __syncthreads();

    if (kbase > wq0 + 31) continue;

    F8 kf[4][2];
#pragma unroll
    for (int ks = 0; ks < 4; ++ks)
#pragma unroll
      for (int nt = 0; nt < 2; ++nt)
        kf[ks][nt].v = *(const short8*)&Klds[(nt * 16 + col) * KST + ks * 32 + quad * 8];

#pragma unroll
    for (int mt = 0; mt < 2; ++mt) {
      floatx4 s0 = {0.f, 0.f, 0.f, 0.f}, s1 = {0.f, 0.f, 0.f, 0.f};
#pragma unroll
      for (int ks = 0; ks < 4; ++ks) {
        s0 = __builtin_amdgcn_mfma_f32_16x16x32_bf16(qf[mt][ks].v, kf[ks][0].v, s0, 0, 0, 0);
        s1 = __builtin_amdgcn_mfma_f32_16x16x32_bf16(qf[mt][ks].v, kf[ks][1].v, s1, 0, 0, 0);
      }
      const int q0 = wq0 + mt * 16 + quad * 4;
      const bool diag = (kbase + 31 > wq0 + mt * 16);
      unsigned short* pw = &Pl[wave][(mt * 16 + quad * 4) * PST];
#pragma unroll
      for (int r = 0; r < 4; ++r) {
        float p0 = __expf(s0[r]);
        float p1 = __expf(s1[r]);
        if (diag) {
          p0 = (kbase + col > q0 + r) ? 0.f : p0;
          p1 = (kbase + 16 + col > q0 + r) ? 0.f : p1;
        }
        lsum[mt][r] += p0 + p1;
        pw[r * PST + col] = f2bf(p0);
        pw[r * PST + 16 + col] = f2bf(p1);
      }
    }
    F8 pa[2];
#pragma unroll
    for (int mt = 0; mt < 2; ++mt)
      pa[mt].v = *(const short8*)&Pl[wave][(mt * 16 + col) * PST + quad * 8];
#pragma unroll
    for (int dt = 0; dt < 8; ++dt) {
      F8 vb;
      vb.v = *(const short8*)&Vt[(dt * 16 + col) * VST + quad * 8];
#pragma unroll
      for (int mt = 0; mt < 2; ++mt)
        acc[mt][dt] = __builtin_amdgcn_mfma_f32_16x16x32_bf16(pa[mt].v, vb.v, acc[mt][dt], 0, 0, 0);
    }
  }

#pragma unroll
  for (int mt = 0; mt < 2; ++mt) {
#pragma unroll
    for (int r = 0; r < 4; ++r) {
      float l = lsum[mt][r];
      l += __shfl_xor(l, 1);
      l += __shfl_xor(l, 2);
      l += __shfl_xor(l, 4);
      l += __shfl_xor(l, 8);
      const float inv = 1.0f / l;
      const int qi = wq0 + mt * 16 + quad * 4 + r;
      float* op = og + ((size_t)(seg + qi) * NH + h) * HD;
#pragma unroll
      for (int dt = 0; dt < 8; ++dt)
        op[dt * 16 + col] = acc[mt][dt][r] * inv;
    }
  }
}

extern "C" void kernel_launch(void* const* d_in, const int* in_sizes, int n_in,
                              void* d_out, int out_size, void* d_ws, size_t ws_size,
                              hipStream_t stream) {
  const float* q = (const float*)d_in[0];
  const float* k = (const float*)d_in[1];
  const float* v = (const float*)d_in[2];
  float* out = (float*)d_out;
  if (ws_size >= (size_t)(8 * 1024 * 1024)) {
    unsigned short* Ktg = (unsigned short*)d_ws;
    unsigned short* Vtg = Ktg + 2097152;  // +4MB
    hipLaunchKernelGGL(prepass, dim3(1024), dim3(256), 0, stream, k, v, Ktg, Vtg);
    hipLaunchKernelGGL(fa_fwd4, dim3(2048), dim3(128), 0, stream, q, Ktg, Vtg, out);
  } else {
    hipLaunchKernelGGL(fa_fwd, dim3(512), dim3(256), 0, stream, q, k, v, out);
  }
}